// Round 2
// baseline (170.030 us; speedup 1.0000x reference)
//
#include <hip/hip_runtime.h>
#include <hip/hip_bf16.h>
#include <stdint.h>

// Problem constants: T=512, B=32, I=512, H=512
#define T_DIM 512
#define B_DIM 32
#define K_DIM 512     // I
#define H_DIM 512
#define N_DIM 1536    // 3*H, gate-packed in h-pairs: n = (h>>1)*6 + (h&1)*3 + g
#define M_DIM 16384   // T*B

typedef __bf16 bf16_t;
typedef bf16_t bf16x8 __attribute__((ext_vector_type(8)));
typedef float floatx4 __attribute__((ext_vector_type(4)));

#define LOG2E 1.442695041f     // 1/ln(2)
#define TWO_LOG2E 2.885390082f

// fp32 -> bf16 (RNE) bit pack, shared by convert_w and the fused GEMM A-stage
__device__ __forceinline__ unsigned int f2bf_bits(float f) {
  uint32_t u = __builtin_bit_cast(uint32_t, f);
  u += 0x7FFFu + ((u >> 16) & 1u);
  return u >> 16;
}

// ---------- W_ih fp32 -> bf16, h-pair gate permute (W only; x is fused) ----
// Wb row (h>>1)*6 + (h&1)*3 + g  <-  original row g*512+h. 384 blocks.
__global__ void convert_w_kernel(const float* __restrict__ W,
                                 unsigned short* __restrict__ Wb) {
  int i = (blockIdx.x * 256 + threadIdx.x) * 8;
  int n = i >> 9;           // packed row
  int k = i & 511;
  int p6 = n / 6;
  int sub = n - p6 * 6;
  int hodd = (sub >= 3) ? 1 : 0;
  int g = sub - hodd * 3;
  int h = p6 * 2 + hodd;
  const float* src = W + ((g << 9) + h) * 512 + k;
  unsigned short* dst = Wb + i;
  const float4* p = (const float4*)src;
  float4 f0 = p[0];
  float4 f1 = p[1];
  uint4 v;
  v.x = f2bf_bits(f0.x) | (f2bf_bits(f0.y) << 16);
  v.y = f2bf_bits(f0.z) | (f2bf_bits(f0.w) << 16);
  v.z = f2bf_bits(f1.x) | (f2bf_bits(f1.y) << 16);
  v.w = f2bf_bits(f1.z) | (f2bf_bits(f1.w) << 16);
  *(uint4*)dst = v;
}

// ---------- bf16 GEMM: NT, 256x128 tile, BK=64, XOR-swizzled LDS ----------
// R9: reverted to the proven R7 2-barrier structure (R8's 8-phase port
// degenerated: 612 TF = 880-steady x 0.75 packing -- m232 failure mode).
// ONE change vs R7: the A operand is read directly from fp32 x and converted
// to bf16 in-kernel (reg-staged: coalesced float4 loads -> RNE pack ->
// swizzled ds_write_b128). This deletes the 4096-block x-convert pass
// (~7.6us of HBM traffic + launch). B keeps global_load_lds from Wb.
// Pack VALU (~112 ops/thread/K-tile) rides the idle VALU pipe (m114
// MFMA/VALU co-issue; VALUBusy was 11%).
// Swizzle involution: LDS slot p of row holds k-chunk p^(row&7); reader
// wants chunk c -> reads slot c^(row&7). Write side: linear global chunk
// kc stored at slot kc^(row&7). Same involution both sides (rule #21).
__global__ __launch_bounds__(512, 4) void gemm_bf16_kernel(
    const float* __restrict__ X, const unsigned short* __restrict__ Bm,
    _Float16* __restrict__ C) {
  __shared__ bf16_t smem[24576];  // [0..16383] A-tile 256x64, [16384..] B-tile
  const int tid = threadIdx.x;
  const int lane = tid & 63;
  const int w = tid >> 6;
  const int tileM = blockIdx.x * 256;
  const int tileN = blockIdx.y * 128;
  const int waveM = w & 3;
  const int waveN = w >> 2;
  const int lm = lane & 15;
  const int lg = lane >> 4;       // 0..3 k-chunk group

  floatx4 acc[4][4] = {};

  for (int k0 = 0; k0 < K_DIM; k0 += 64) {
    // B first: get the DMA in flight before the A load/pack sequence.
    // 1024 16B chunks (128 rows x 8), 2 groups of 512.
#pragma unroll
    for (int g = 0; g < 2; ++g) {
      int s = g * 512 + tid;
      int row = s >> 3;
      int kc = (s & 7) ^ (row & 7);  // source chunk under swizzle
      bf16_t* lb = smem + 16384 + (g * 512 + w * 64) * 8;
      const unsigned short* gb = Bm + (size_t)(tileN + row) * K_DIM + k0 + kc * 8;
      __builtin_amdgcn_global_load_lds(
          (const __attribute__((address_space(1))) unsigned int*)gb,
          (__attribute__((address_space(3))) unsigned int*)lb, 16, 0, 0);
    }
    // A: 2048 chunks (256 rows x 8), 4 per thread. fp32 source (coalesced:
    // consecutive lanes -> consecutive 32B), pack to bf16x8, store to the
    // swizzled slot.
#pragma unroll
    for (int g = 0; g < 4; ++g) {
      int s = g * 512 + tid;
      int row = s >> 3;
      int kc = s & 7;               // LINEAR global chunk
      const float4* gs =
          (const float4*)(X + (size_t)(tileM + row) * K_DIM + k0 + kc * 8);
      float4 f0 = gs[0];
      float4 f1 = gs[1];
      uint4 v;
      v.x = f2bf_bits(f0.x) | (f2bf_bits(f0.y) << 16);
      v.y = f2bf_bits(f0.z) | (f2bf_bits(f0.w) << 16);
      v.z = f2bf_bits(f1.x) | (f2bf_bits(f1.y) << 16);
      v.w = f2bf_bits(f1.z) | (f2bf_bits(f1.w) << 16);
      *(uint4*)(smem + (size_t)(row * 8 + (kc ^ (row & 7))) * 8) = v;
    }
    __syncthreads();  // drains vmcnt (B DMA) + lgkm (A ds_writes)

#pragma unroll
    for (int ks = 0; ks < 2; ++ks) {
      bf16x8 af[4], bfg[4];
#pragma unroll
      for (int i = 0; i < 4; ++i) {
        int row = waveM * 64 + i * 16 + lm;
        int c = ks * 4 + lg;
        af[i] = *(const bf16x8*)(smem + row * 64 + (c ^ (row & 7)) * 8);
      }
#pragma unroll
      for (int j = 0; j < 4; ++j) {
        int row = waveN * 64 + j * 16 + lm;
        int c = ks * 4 + lg;
        bfg[j] = *(const bf16x8*)(smem + 16384 + row * 64 + (c ^ (row & 7)) * 8);
      }
#pragma unroll
      for (int i = 0; i < 4; ++i)
#pragma unroll
        for (int j = 0; j < 4; ++j)
          acc[i][j] = __builtin_amdgcn_mfma_f32_16x16x32_bf16(af[i], bfg[j],
                                                              acc[i][j], 0, 0, 0);
    }
    __syncthreads();  // also guarantees smem reusable for the epilogue
  }

  // Epilogue. MFMA C/D layout: col=lane&15 (+16j), row=(lane>>4)*4+reg (+16i).
  // Two passes of 32 rows through a 4KB wave-private LDS region, read back as
  // 4-col quads -> 16 lanes x 8B = 128B contiguous stores (full lines).
  _Float16* ep = (_Float16*)smem + w * 2048;  // 32x64 fp16 per wave
  const int q = lm;            // col quad 0..15
  const int rgrp = lane >> 4;  // 0..3
  const size_t crow0 = (size_t)(tileM + waveM * 64);
  const int ccol = tileN + waveN * 64 + q * 4;
#pragma unroll
  for (int p = 0; p < 2; ++p) {
#pragma unroll
    for (int il = 0; il < 2; ++il) {
      const int i = 2 * p + il;
#pragma unroll
      for (int j = 0; j < 4; ++j) {
        const int cl = lm + j * 16;
        const int sub = (tileN + waveN * 64 + cl) % 6;
        const float scl = (sub == 2 || sub == 5) ? TWO_LOG2E : -LOG2E;
#pragma unroll
        for (int r = 0; r < 4; ++r) {
          int rl = (lane >> 4) * 4 + r + 16 * il;  // 0..31
          ep[rl * 64 + cl] = (_Float16)(scl * acc[i][j][r]);
        }
      }
    }
    // wave-private region: DS ops within a wave are ordered; no barrier
#pragma unroll
    for (int k = 0; k < 8; ++k) {
      int rl = rgrp + 4 * k;  // 0..31
      uint2 v = *(const uint2*)(ep + rl * 64 + q * 4);
      *(uint2*)(C + (crow0 + p * 32 + rl) * N_DIM + ccol) = v;
    }
  }
}

// ---------- diagonal GRU scan (unchanged) ----------
__global__ __launch_bounds__(64) void indgru_scan_kernel(
    const _Float16* __restrict__ gx, const float* __restrict__ h0,
    const float* __restrict__ w_hh, float* __restrict__ out,
    float* __restrict__ hlast) {
  const int idx = blockIdx.x * 64 + threadIdx.x;  // 0..16383
  const int b = idx >> 9;
  const int h = idx & (H_DIM - 1);
  const float wr = -LOG2E * w_hh[h];
  const float wz = -LOG2E * w_hh[H_DIM + h];
  const float wn = TWO_LOG2E * w_hh[2 * H_DIM + h];
  const int sh = (h & 1) << 4;  // funnel shift: 0 or 16 bits
  float hv = h0[idx];

  const char* base = (const char*)(gx + (size_t)b * N_DIM + (h >> 1) * 6) + ((h & 1) << 2);
  float* outp = out + (size_t)b * H_DIM + h;  // t-stride 16384 fp32

  constexpr int D = 32;
  constexpr size_t TSTRIDE = (size_t)B_DIM * N_DIM * sizeof(_Float16);  // 98304 B
  uint2 pq[D];
#pragma unroll
  for (int t = 0; t < D; ++t)
    pq[t] = *(const uint2*)(base + (size_t)t * TSTRIDE);

  auto cvt16 = [](uint32_t bits) {
    return (float)__builtin_bit_cast(_Float16, (unsigned short)bits);
  };

  for (int t0 = 0; t0 < T_DIM - D; t0 += D) {
#pragma unroll
    for (int s = 0; s < D; ++s) {
      const int t = t0 + s;
      uint2 qv = pq[s];
      pq[s] = *(const uint2*)(base + (size_t)(t + D) * TSTRIDE);
      asm volatile("" ::: "memory");  // pin prefetch distance
      uint64_t v = (((uint64_t)qv.y << 32) | qv.x) >> sh;
      float gr = cvt16((uint32_t)v);
      float gz = cvt16((uint32_t)(v >> 16));
      float gn = cvt16((uint32_t)(v >> 32));
      float ar = fmaf(wr, hv, gr);
      float az = fmaf(wz, hv, gz);
      float t1 = wn * hv;
      float er = __builtin_amdgcn_exp2f(ar);
      float ez = __builtin_amdgcn_exp2f(az);
      float r = __builtin_amdgcn_rcpf(1.0f + er);
      float z = __builtin_amdgcn_rcpf(1.0f + ez);
      float en = __builtin_amdgcn_exp2f(fmaf(r, t1, gn));
      float u = __builtin_amdgcn_rcpf(1.0f + en);
      float n = fmaf(-2.0f, u, 1.0f);
      float zh = z * hv;
      float omz = 1.0f - z;
      hv = fmaf(n, omz, zh);
      outp[(size_t)t * (B_DIM * H_DIM)] = hv;
    }
  }
#pragma unroll
  for (int s = 0; s < D; ++s) {
    const int t = T_DIM - D + s;
    uint2 qv = pq[s];
    uint64_t v = (((uint64_t)qv.y << 32) | qv.x) >> sh;
    float gr = cvt16((uint32_t)v);
    float gz = cvt16((uint32_t)(v >> 16));
    float gn = cvt16((uint32_t)(v >> 32));
    float ar = fmaf(wr, hv, gr);
    float az = fmaf(wz, hv, gz);
    float t1 = wn * hv;
    float er = __builtin_amdgcn_exp2f(ar);
    float ez = __builtin_amdgcn_exp2f(az);
    float r = __builtin_amdgcn_rcpf(1.0f + er);
    float z = __builtin_amdgcn_rcpf(1.0f + ez);
    float en = __builtin_amdgcn_exp2f(fmaf(r, t1, gn));
    float u = __builtin_amdgcn_rcpf(1.0f + en);
    float n = fmaf(-2.0f, u, 1.0f);
    float zh = z * hv;
    float omz = 1.0f - z;
    hv = fmaf(n, omz, zh);
    outp[(size_t)t * (B_DIM * H_DIM)] = hv;
  }
  hlast[idx] = hv;
}

extern "C" void kernel_launch(void* const* d_in, const int* in_sizes, int n_in,
                              void* d_out, int out_size, void* d_ws, size_t ws_size,
                              hipStream_t stream) {
  const float* x    = (const float*)d_in[0];   // (T,B,I)  = 8388608
  const float* h0   = (const float*)d_in[1];   // (B,H)    = 16384
  const float* W_ih = (const float*)d_in[2];   // (3H,I)   = 786432
  const float* w_hh = (const float*)d_in[3];   // (3,H)    = 1536

  float* out = (float*)d_out;                          // (T,B,H)
  float* hlast = out + (size_t)T_DIM * B_DIM * H_DIM;  // (1,B,H)

  // workspace: Wb(bf16 1536x512) 1.5 MB | gx(fp16) 50 MB
  char* ws = (char*)d_ws;
  unsigned short* Wb = (unsigned short*)ws;
  _Float16* gx = (_Float16*)(ws + 1572864);

  convert_w_kernel<<<384, 256, 0, stream>>>(W_ih, Wb);

  dim3 grid(M_DIM / 256, N_DIM / 128);  // 64 x 12
  gemm_bf16_kernel<<<grid, 512, 0, stream>>>(x, Wb, gx);

  indgru_scan_kernel<<<256, 64, 0, stream>>>(gx, h0, w_hh, out, hlast);
}

// Round 5
// 149.923 us; speedup vs baseline: 1.1341x; 1.1341x over previous
//
#include <hip/hip_runtime.h>
#include <hip/hip_bf16.h>
#include <stdint.h>

// Problem constants: T=512, B=32, I=512, H=512
#define T_DIM 512
#define B_DIM 32
#define K_DIM 512     // I
#define H_DIM 512
#define N_DIM 1536    // 3*H, gate-packed in h-pairs: n = (h>>1)*6 + (h&1)*3 + g
#define M_DIM 16384   // T*B

typedef __bf16 bf16_t;
typedef bf16_t bf16x8 __attribute__((ext_vector_type(8)));
typedef float floatx4 __attribute__((ext_vector_type(4)));

#define LOG2E 1.442695041f     // 1/ln(2)
#define TWO_LOG2E 2.885390082f

// ---------- fp32 -> bf16 (RNE), 8 elems/thread, both inputs fused ----------
// (R0 version restored: R2's in-GEMM x-convert re-read fp32 A 12x -> FETCH
// 22.6->42MB, GEMM 39->66.5us. One-shot convert is the right trade.)
__device__ __forceinline__ unsigned int f2bf_bits(float f) {
  uint32_t u = __builtin_bit_cast(uint32_t, f);
  u += 0x7FFFu + ((u >> 16) & 1u);
  return u >> 16;
}

__global__ void convert_both_kernel(const float* __restrict__ x,
                                    unsigned short* __restrict__ xb,
                                    const float* __restrict__ W,
                                    unsigned short* __restrict__ Wb) {
  int bid = blockIdx.x;
  const float* src;
  unsigned short* dst;
  int i;
  if (bid < 4096) {           // x: 8388608 elems, identity convert
    i = (bid * 256 + threadIdx.x) * 8;
    src = x + i;
    dst = xb + i;
  } else {                    // Wb: 1536 rows x 512, h-pair permuted
    i = ((bid - 4096) * 256 + threadIdx.x) * 8;
    int n = i >> 9;           // packed row
    int k = i & 511;
    int p6 = n / 6;
    int sub = n - p6 * 6;
    int hodd = (sub >= 3) ? 1 : 0;
    int g = sub - hodd * 3;
    int h = p6 * 2 + hodd;
    src = W + ((g << 9) + h) * 512 + k;
    dst = Wb + i;
  }
  const float4* p = (const float4*)src;
  float4 f0 = p[0];
  float4 f1 = p[1];
  uint4 v;
  v.x = f2bf_bits(f0.x) | (f2bf_bits(f0.y) << 16);
  v.y = f2bf_bits(f0.z) | (f2bf_bits(f0.w) << 16);
  v.z = f2bf_bits(f1.x) | (f2bf_bits(f1.y) << 16);
  v.w = f2bf_bits(f1.z) | (f2bf_bits(f1.w) << 16);
  *(uint4*)dst = v;
}

// ---------- bf16 GEMM: NT, 256x128 tile, BK=64, XOR-swizzled LDS ----------
// R10/R11/R12 = R0 structure exactly (proven ~39us) + ONE change: 1D grid
// with A-band-major decomposition and XCD-chunked swizzle (T1).
//   id -> (m = id/12, n = id%12): the 12 N-blocks sharing one 256KB A-band
//   are consecutive; swz = (id&7)*96 + id/8 gives each XCD a contiguous
//   96-block chunk (8 A-bands x 12 N). Per-XCD L2 working set: ~3 live
//   A-bands (0.75MB) + full B (1.5MB) << 4MB. A re-reads (12x, 201MB
//   aggregate) become L2 hits instead of L3 round-trips -> the per-K-iter
//   barrier-drain tail chunk is ~200cy (L2) not ~450-900cy (L3/HBM).
//   768 % 8 == 0 -> the simple chunked swizzle is bijective (ERRATA #11).
// (R3/R4 benches were container/broker failures -- kernel never executed;
//  audit found no device-side mechanism; resubmitted unchanged. If this
//  fails again: next round submits byte-exact R0 to disambiguate.)
__global__ __launch_bounds__(512, 4) void gemm_bf16_kernel(
    const unsigned short* __restrict__ A, const unsigned short* __restrict__ Bm,
    _Float16* __restrict__ C) {
  __shared__ bf16_t smem[24576];  // [0..16383] A-tile 256x64, [16384..] B-tile
  const int tid = threadIdx.x;
  const int lane = tid & 63;
  const int w = tid >> 6;
  // XCD-chunked, A-band-major block swizzle
  const int id = blockIdx.x;                  // 0..767
  const int swz = (id & 7) * 96 + (id >> 3);  // bijective: 768 = 8*96
  const int mIdx = swz / 12;
  const int nIdx = swz - mIdx * 12;
  const int tileM = mIdx * 256;
  const int tileN = nIdx * 128;
  const int waveM = w & 3;
  const int waveN = w >> 2;
  const int lm = lane & 15;
  const int lg = lane >> 4;       // 0..3 k-chunk group

  floatx4 acc[4][4] = {};

  for (int k0 = 0; k0 < K_DIM; k0 += 64) {
    // A: 2048 16B chunks (256 rows x 8), 4 groups of 512
#pragma unroll
    for (int g = 0; g < 4; ++g) {
      int s = g * 512 + tid;
      int row = s >> 3;
      int kc = (s & 7) ^ (row & 7);  // source chunk under swizzle
      bf16_t* la = smem + (g * 512 + w * 64) * 8;
      const unsigned short* ga = A + (size_t)(tileM + row) * K_DIM + k0 + kc * 8;
      __builtin_amdgcn_global_load_lds(
          (const __attribute__((address_space(1))) unsigned int*)ga,
          (__attribute__((address_space(3))) unsigned int*)la, 16, 0, 0);
    }
    // B: 1024 chunks (128 rows x 8), 2 groups of 512
#pragma unroll
    for (int g = 0; g < 2; ++g) {
      int s = g * 512 + tid;
      int row = s >> 3;
      int kc = (s & 7) ^ (row & 7);
      bf16_t* lb = smem + 16384 + (g * 512 + w * 64) * 8;
      const unsigned short* gb = Bm + (size_t)(tileN + row) * K_DIM + k0 + kc * 8;
      __builtin_amdgcn_global_load_lds(
          (const __attribute__((address_space(1))) unsigned int*)gb,
          (__attribute__((address_space(3))) unsigned int*)lb, 16, 0, 0);
    }
    __syncthreads();

#pragma unroll
    for (int ks = 0; ks < 2; ++ks) {
      bf16x8 af[4], bfg[4];
#pragma unroll
      for (int i = 0; i < 4; ++i) {
        int row = waveM * 64 + i * 16 + lm;
        int c = ks * 4 + lg;
        af[i] = *(const bf16x8*)(smem + row * 64 + (c ^ (row & 7)) * 8);
      }
#pragma unroll
      for (int j = 0; j < 4; ++j) {
        int row = waveN * 64 + j * 16 + lm;
        int c = ks * 4 + lg;
        bfg[j] = *(const bf16x8*)(smem + 16384 + row * 64 + (c ^ (row & 7)) * 8);
      }
#pragma unroll
      for (int i = 0; i < 4; ++i)
#pragma unroll
        for (int j = 0; j < 4; ++j)
          acc[i][j] = __builtin_amdgcn_mfma_f32_16x16x32_bf16(af[i], bfg[j],
                                                              acc[i][j], 0, 0, 0);
    }
    __syncthreads();  // also guarantees smem reusable for the epilogue
  }

  // Epilogue. MFMA C/D layout: col=lane&15 (+16j), row=(lane>>4)*4+reg (+16i).
  // Two passes of 32 rows through a 4KB wave-private LDS region, read back as
  // 4-col quads -> 16 lanes x 8B = 128B contiguous stores (full lines).
  _Float16* ep = (_Float16*)smem + w * 2048;  // 32x64 fp16 per wave
  const int q = lm;            // col quad 0..15
  const int rgrp = lane >> 4;  // 0..3
  const size_t crow0 = (size_t)(tileM + waveM * 64);
  const int ccol = tileN + waveN * 64 + q * 4;
#pragma unroll
  for (int p = 0; p < 2; ++p) {
#pragma unroll
    for (int il = 0; il < 2; ++il) {
      const int i = 2 * p + il;
#pragma unroll
      for (int j = 0; j < 4; ++j) {
        const int cl = lm + j * 16;
        const int sub = (tileN + waveN * 64 + cl) % 6;
        const float scl = (sub == 2 || sub == 5) ? TWO_LOG2E : -LOG2E;
#pragma unroll
        for (int r = 0; r < 4; ++r) {
          int rl = (lane >> 4) * 4 + r + 16 * il;  // 0..31
          ep[rl * 64 + cl] = (_Float16)(scl * acc[i][j][r]);
        }
      }
    }
    // wave-private region: DS ops within a wave are ordered; no barrier
#pragma unroll
    for (int k = 0; k < 8; ++k) {
      int rl = rgrp + 4 * k;  // 0..31
      uint2 v = *(const uint2*)(ep + rl * 64 + q * 4);
      *(uint2*)(C + (crow0 + p * 32 + rl) * N_DIM + ccol) = v;
    }
  }
}

// ---------- diagonal GRU scan (unchanged) ----------
__global__ __launch_bounds__(64) void indgru_scan_kernel(
    const _Float16* __restrict__ gx, const float* __restrict__ h0,
    const float* __restrict__ w_hh, float* __restrict__ out,
    float* __restrict__ hlast) {
  const int idx = blockIdx.x * 64 + threadIdx.x;  // 0..16383
  const int b = idx >> 9;
  const int h = idx & (H_DIM - 1);
  const float wr = -LOG2E * w_hh[h];
  const float wz = -LOG2E * w_hh[H_DIM + h];
  const float wn = TWO_LOG2E * w_hh[2 * H_DIM + h];
  const int sh = (h & 1) << 4;  // funnel shift: 0 or 16 bits
  float hv = h0[idx];

  const char* base = (const char*)(gx + (size_t)b * N_DIM + (h >> 1) * 6) + ((h & 1) << 2);
  float* outp = out + (size_t)b * H_DIM + h;  // t-stride 16384 fp32

  constexpr int D = 32;
  constexpr size_t TSTRIDE = (size_t)B_DIM * N_DIM * sizeof(_Float16);  // 98304 B
  uint2 pq[D];
#pragma unroll
  for (int t = 0; t < D; ++t)
    pq[t] = *(const uint2*)(base + (size_t)t * TSTRIDE);

  auto cvt16 = [](uint32_t bits) {
    return (float)__builtin_bit_cast(_Float16, (unsigned short)bits);
  };

  for (int t0 = 0; t0 < T_DIM - D; t0 += D) {
#pragma unroll
    for (int s = 0; s < D; ++s) {
      const int t = t0 + s;
      uint2 qv = pq[s];
      pq[s] = *(const uint2*)(base + (size_t)(t + D) * TSTRIDE);
      asm volatile("" ::: "memory");  // pin prefetch distance
      uint64_t v = (((uint64_t)qv.y << 32) | qv.x) >> sh;
      float gr = cvt16((uint32_t)v);
      float gz = cvt16((uint32_t)(v >> 16));
      float gn = cvt16((uint32_t)(v >> 32));
      float ar = fmaf(wr, hv, gr);
      float az = fmaf(wz, hv, gz);
      float t1 = wn * hv;
      float er = __builtin_amdgcn_exp2f(ar);
      float ez = __builtin_amdgcn_exp2f(az);
      float r = __builtin_amdgcn_rcpf(1.0f + er);
      float z = __builtin_amdgcn_rcpf(1.0f + ez);
      float en = __builtin_amdgcn_exp2f(fmaf(r, t1, gn));
      float u = __builtin_amdgcn_rcpf(1.0f + en);
      float n = fmaf(-2.0f, u, 1.0f);
      float zh = z * hv;
      float omz = 1.0f - z;
      hv = fmaf(n, omz, zh);
      outp[(size_t)t * (B_DIM * H_DIM)] = hv;
    }
  }
#pragma unroll
  for (int s = 0; s < D; ++s) {
    const int t = T_DIM - D + s;
    uint2 qv = pq[s];
    uint64_t v = (((uint64_t)qv.y << 32) | qv.x) >> sh;
    float gr = cvt16((uint32_t)v);
    float gz = cvt16((uint32_t)(v >> 16));
    float gn = cvt16((uint32_t)(v >> 32));
    float ar = fmaf(wr, hv, gr);
    float az = fmaf(wz, hv, gz);
    float t1 = wn * hv;
    float er = __builtin_amdgcn_exp2f(ar);
    float ez = __builtin_amdgcn_exp2f(az);
    float r = __builtin_amdgcn_rcpf(1.0f + er);
    float z = __builtin_amdgcn_rcpf(1.0f + ez);
    float en = __builtin_amdgcn_exp2f(fmaf(r, t1, gn));
    float u = __builtin_amdgcn_rcpf(1.0f + en);
    float n = fmaf(-2.0f, u, 1.0f);
    float zh = z * hv;
    float omz = 1.0f - z;
    hv = fmaf(n, omz, zh);
    outp[(size_t)t * (B_DIM * H_DIM)] = hv;
  }
  hlast[idx] = hv;
}

extern "C" void kernel_launch(void* const* d_in, const int* in_sizes, int n_in,
                              void* d_out, int out_size, void* d_ws, size_t ws_size,
                              hipStream_t stream) {
  const float* x    = (const float*)d_in[0];   // (T,B,I)  = 8388608
  const float* h0   = (const float*)d_in[1];   // (B,H)    = 16384
  const float* W_ih = (const float*)d_in[2];   // (3H,I)   = 786432
  const float* w_hh = (const float*)d_in[3];   // (3,H)    = 1536

  float* out = (float*)d_out;                          // (T,B,H)
  float* hlast = out + (size_t)T_DIM * B_DIM * H_DIM;  // (1,B,H)

  // workspace: xb(bf16) 16 MB | Wb(bf16 1536x512) 1.5 MB | gx(fp16) 50 MB
  char* ws = (char*)d_ws;
  unsigned short* xb = (unsigned short*)ws;
  unsigned short* Wb = (unsigned short*)(ws + 16777216);
  _Float16* gx = (_Float16*)(ws + 16777216 + 1572864);

  convert_both_kernel<<<4480, 256, 0, stream>>>(x, xb, W_ih, Wb);

  gemm_bf16_kernel<<<768, 512, 0, stream>>>(xb, Wb, gx);

  indgru_scan_kernel<<<256, 64, 0, stream>>>(gx, h0, w_hh, out, hlast);
}

// Round 6
// 149.095 us; speedup vs baseline: 1.1404x; 1.0056x over previous
//
#include <hip/hip_runtime.h>
#include <hip/hip_bf16.h>
#include <stdint.h>

// Problem constants: T=512, B=32, I=512, H=512
#define T_DIM 512
#define B_DIM 32
#define K_DIM 512     // I
#define H_DIM 512
#define N_DIM 1536    // 3*H, gate-packed in h-pairs: n = (h>>1)*6 + (h&1)*3 + g
#define M_DIM 16384   // T*B

typedef __bf16 bf16_t;
typedef bf16_t bf16x8 __attribute__((ext_vector_type(8)));
typedef float floatx4 __attribute__((ext_vector_type(4)));

#define LOG2E 1.442695041f     // 1/ln(2)
#define TWO_LOG2E 2.885390082f

// ---------- fp32 -> bf16 (RNE), 8 elems/thread, both inputs fused ----------
__device__ __forceinline__ unsigned int f2bf_bits(float f) {
  uint32_t u = __builtin_bit_cast(uint32_t, f);
  u += 0x7FFFu + ((u >> 16) & 1u);
  return u >> 16;
}

__global__ void convert_both_kernel(const float* __restrict__ x,
                                    unsigned short* __restrict__ xb,
                                    const float* __restrict__ W,
                                    unsigned short* __restrict__ Wb) {
  int bid = blockIdx.x;
  const float* src;
  unsigned short* dst;
  int i;
  if (bid < 4096) {           // x: 8388608 elems, identity convert
    i = (bid * 256 + threadIdx.x) * 8;
    src = x + i;
    dst = xb + i;
  } else {                    // Wb: 1536 rows x 512, h-pair permuted
    i = ((bid - 4096) * 256 + threadIdx.x) * 8;
    int n = i >> 9;           // packed row
    int k = i & 511;
    int p6 = n / 6;
    int sub = n - p6 * 6;
    int hodd = (sub >= 3) ? 1 : 0;
    int g = sub - hodd * 3;
    int h = p6 * 2 + hodd;
    src = W + ((g << 9) + h) * 512 + k;
    dst = Wb + i;
  }
  const float4* p = (const float4*)src;
  float4 f0 = p[0];
  float4 f1 = p[1];
  uint4 v;
  v.x = f2bf_bits(f0.x) | (f2bf_bits(f0.y) << 16);
  v.y = f2bf_bits(f0.z) | (f2bf_bits(f0.w) << 16);
  v.z = f2bf_bits(f1.x) | (f2bf_bits(f1.y) << 16);
  v.w = f2bf_bits(f1.z) | (f2bf_bits(f1.w) << 16);
  *(uint4*)dst = v;
}

// ---------- bf16 GEMM: NT, 256x128 tile, BK=64, double-buffered LDS -------
// R13 theory: the 2-barrier loop is staging-DELIVERY-bound: 302MB staged at
// 12.6 B/cy/CU effective -- ingress idles at every vmcnt(0)+barrier drain
// (issue->wait with no compute between). Fix: LDS double buffer (96KB ->
// 1 block/CU, 768 blocks = 3 exact rounds), ONE barrier per K-iter:
//   stage(buf0,0); sync;
//   for t: { if(t<7) stage(buf[t+1], t+1);   // issue-early, no wait
//            compute(buf[t]);                 // hides t+1's HBM/L2 latency
//            sync; }                          // compiler vmcnt(0) drains t+1
// No manual vmcnt (R1's failure mode): the compiler's conservative
// drain-at-barrier is correct AND cheap because issue happened ~compute-time
// earlier. Race check: stage(t+1) writes buf[(t+1)&1], whose last readers
// (compute(t-1)) finished before sync(t-1); compute(t) reads buf[t&1],
// drained by sync(t-1). Epilogue reuses buf0's A region after final sync
// (last reader of buf0 was compute(t=6)).
// Kept: T1 XCD/A-band-major block swizzle (R5, measured win), BK=64 XOR
// LDS swizzle, epilogue transpose -- ep stride padded 64->68 fp16 to kill
// the 786K measured bank-conflict cycles (rows shift 2 banks/row).
__global__ __launch_bounds__(512, 4) void gemm_bf16_kernel(
    const unsigned short* __restrict__ A, const unsigned short* __restrict__ Bm,
    _Float16* __restrict__ C) {
  __shared__ bf16_t smem[49152];  // 2 x (A 256x64 | B 128x64) = 96KB
  const int tid = threadIdx.x;
  const int lane = tid & 63;
  const int w = tid >> 6;
  // XCD-chunked, A-band-major block swizzle (bijective: 768 = 8*96)
  const int id = blockIdx.x;
  const int swz = (id & 7) * 96 + (id >> 3);
  const int mIdx = swz / 12;
  const int nIdx = swz - mIdx * 12;
  const int tileM = mIdx * 256;
  const int tileN = nIdx * 128;
  const int waveM = w & 3;
  const int waveN = w >> 2;
  const int lm = lane & 15;
  const int lg = lane >> 4;       // 0..3 k-chunk group

  floatx4 acc[4][4] = {};

  // stage one full K-tile (A 32KB + B 16KB) into buffer `buf`, 6 loads/thread
  auto stage = [&](int buf, int k0) {
    bf16_t* base = smem + buf * 24576;
#pragma unroll
    for (int g = 0; g < 4; ++g) {
      int s = g * 512 + tid;
      int row = s >> 3;
      int kc = (s & 7) ^ (row & 7);  // source chunk under swizzle
      bf16_t* la = base + (g * 512 + w * 64) * 8;
      const unsigned short* ga = A + (size_t)(tileM + row) * K_DIM + k0 + kc * 8;
      __builtin_amdgcn_global_load_lds(
          (const __attribute__((address_space(1))) unsigned int*)ga,
          (__attribute__((address_space(3))) unsigned int*)la, 16, 0, 0);
    }
#pragma unroll
    for (int g = 0; g < 2; ++g) {
      int s = g * 512 + tid;
      int row = s >> 3;
      int kc = (s & 7) ^ (row & 7);
      bf16_t* lb = base + 16384 + (g * 512 + w * 64) * 8;
      const unsigned short* gb = Bm + (size_t)(tileN + row) * K_DIM + k0 + kc * 8;
      __builtin_amdgcn_global_load_lds(
          (const __attribute__((address_space(1))) unsigned int*)gb,
          (__attribute__((address_space(3))) unsigned int*)lb, 16, 0, 0);
    }
  };

  stage(0, 0);
  __syncthreads();  // prologue drain

#pragma unroll
  for (int t = 0; t < 8; ++t) {
    if (t < 7) stage((t + 1) & 1, (t + 1) * 64);  // issue-early, no wait
    const bf16_t* As = smem + (t & 1) * 24576;
    const bf16_t* Bs = As + 16384;
#pragma unroll
    for (int ks = 0; ks < 2; ++ks) {
      bf16x8 af[4], bfg[4];
#pragma unroll
      for (int i = 0; i < 4; ++i) {
        int row = waveM * 64 + i * 16 + lm;
        int c = ks * 4 + lg;
        af[i] = *(const bf16x8*)(As + row * 64 + (c ^ (row & 7)) * 8);
      }
#pragma unroll
      for (int j = 0; j < 4; ++j) {
        int row = waveN * 64 + j * 16 + lm;
        int c = ks * 4 + lg;
        bfg[j] = *(const bf16x8*)(Bs + row * 64 + (c ^ (row & 7)) * 8);
      }
#pragma unroll
      for (int i = 0; i < 4; ++i)
#pragma unroll
        for (int j = 0; j < 4; ++j)
          acc[i][j] = __builtin_amdgcn_mfma_f32_16x16x32_bf16(af[i], bfg[j],
                                                              acc[i][j], 0, 0, 0);
    }
    __syncthreads();  // drains next tile's DMA (issued before compute) + joins
  }

  // Epilogue. MFMA C/D layout: col=lane&15 (+16j), row=(lane>>4)*4+reg (+16i).
  // Two passes of 32 rows through a wave-private LDS region (stride 68 fp16:
  // rows shift 2 banks -> no same-bank pile-up), read back as 4-col quads ->
  // 16 lanes x 8B = 128B contiguous stores (full lines).
  _Float16* ep = (_Float16*)smem + w * 2176;  // 32x68 fp16 per wave
  const int q = lm;            // col quad 0..15
  const int rgrp = lane >> 4;  // 0..3
  const size_t crow0 = (size_t)(tileM + waveM * 64);
  const int ccol = tileN + waveN * 64 + q * 4;
#pragma unroll
  for (int p = 0; p < 2; ++p) {
#pragma unroll
    for (int il = 0; il < 2; ++il) {
      const int i = 2 * p + il;
#pragma unroll
      for (int j = 0; j < 4; ++j) {
        const int cl = lm + j * 16;
        const int sub = (tileN + waveN * 64 + cl) % 6;
        const float scl = (sub == 2 || sub == 5) ? TWO_LOG2E : -LOG2E;
#pragma unroll
        for (int r = 0; r < 4; ++r) {
          int rl = (lane >> 4) * 4 + r + 16 * il;  // 0..31
          ep[rl * 68 + cl] = (_Float16)(scl * acc[i][j][r]);
        }
      }
    }
    // wave-private region: DS ops within a wave are ordered; no barrier
#pragma unroll
    for (int k = 0; k < 8; ++k) {
      int rl = rgrp + 4 * k;  // 0..31
      uint2 v = *(const uint2*)(ep + rl * 68 + q * 4);
      *(uint2*)(C + (crow0 + p * 32 + rl) * N_DIM + ccol) = v;
    }
  }
}

// ---------- diagonal GRU scan (unchanged) ----------
__global__ __launch_bounds__(64) void indgru_scan_kernel(
    const _Float16* __restrict__ gx, const float* __restrict__ h0,
    const float* __restrict__ w_hh, float* __restrict__ out,
    float* __restrict__ hlast) {
  const int idx = blockIdx.x * 64 + threadIdx.x;  // 0..16383
  const int b = idx >> 9;
  const int h = idx & (H_DIM - 1);
  const float wr = -LOG2E * w_hh[h];
  const float wz = -LOG2E * w_hh[H_DIM + h];
  const float wn = TWO_LOG2E * w_hh[2 * H_DIM + h];
  const int sh = (h & 1) << 4;  // funnel shift: 0 or 16 bits
  float hv = h0[idx];

  const char* base = (const char*)(gx + (size_t)b * N_DIM + (h >> 1) * 6) + ((h & 1) << 2);
  float* outp = out + (size_t)b * H_DIM + h;  // t-stride 16384 fp32

  constexpr int D = 32;
  constexpr size_t TSTRIDE = (size_t)B_DIM * N_DIM * sizeof(_Float16);  // 98304 B
  uint2 pq[D];
#pragma unroll
  for (int t = 0; t < D; ++t)
    pq[t] = *(const uint2*)(base + (size_t)t * TSTRIDE);

  auto cvt16 = [](uint32_t bits) {
    return (float)__builtin_bit_cast(_Float16, (unsigned short)bits);
  };

  for (int t0 = 0; t0 < T_DIM - D; t0 += D) {
#pragma unroll
    for (int s = 0; s < D; ++s) {
      const int t = t0 + s;
      uint2 qv = pq[s];
      pq[s] = *(const uint2*)(base + (size_t)(t + D) * TSTRIDE);
      asm volatile("" ::: "memory");  // pin prefetch distance
      uint64_t v = (((uint64_t)qv.y << 32) | qv.x) >> sh;
      float gr = cvt16((uint32_t)v);
      float gz = cvt16((uint32_t)(v >> 16));
      float gn = cvt16((uint32_t)(v >> 32));
      float ar = fmaf(wr, hv, gr);
      float az = fmaf(wz, hv, gz);
      float t1 = wn * hv;
      float er = __builtin_amdgcn_exp2f(ar);
      float ez = __builtin_amdgcn_exp2f(az);
      float r = __builtin_amdgcn_rcpf(1.0f + er);
      float z = __builtin_amdgcn_rcpf(1.0f + ez);
      float en = __builtin_amdgcn_exp2f(fmaf(r, t1, gn));
      float u = __builtin_amdgcn_rcpf(1.0f + en);
      float n = fmaf(-2.0f, u, 1.0f);
      float zh = z * hv;
      float omz = 1.0f - z;
      hv = fmaf(n, omz, zh);
      outp[(size_t)t * (B_DIM * H_DIM)] = hv;
    }
  }
#pragma unroll
  for (int s = 0; s < D; ++s) {
    const int t = T_DIM - D + s;
    uint2 qv = pq[s];
    uint64_t v = (((uint64_t)qv.y << 32) | qv.x) >> sh;
    float gr = cvt16((uint32_t)v);
    float gz = cvt16((uint32_t)(v >> 16));
    float gn = cvt16((uint32_t)(v >> 32));
    float ar = fmaf(wr, hv, gr);
    float az = fmaf(wz, hv, gz);
    float t1 = wn * hv;
    float er = __builtin_amdgcn_exp2f(ar);
    float ez = __builtin_amdgcn_exp2f(az);
    float r = __builtin_amdgcn_rcpf(1.0f + er);
    float z = __builtin_amdgcn_rcpf(1.0f + ez);
    float en = __builtin_amdgcn_exp2f(fmaf(r, t1, gn));
    float u = __builtin_amdgcn_rcpf(1.0f + en);
    float n = fmaf(-2.0f, u, 1.0f);
    float zh = z * hv;
    float omz = 1.0f - z;
    hv = fmaf(n, omz, zh);
    outp[(size_t)t * (B_DIM * H_DIM)] = hv;
  }
  hlast[idx] = hv;
}

extern "C" void kernel_launch(void* const* d_in, const int* in_sizes, int n_in,
                              void* d_out, int out_size, void* d_ws, size_t ws_size,
                              hipStream_t stream) {
  const float* x    = (const float*)d_in[0];   // (T,B,I)  = 8388608
  const float* h0   = (const float*)d_in[1];   // (B,H)    = 16384
  const float* W_ih = (const float*)d_in[2];   // (3H,I)   = 786432
  const float* w_hh = (const float*)d_in[3];   // (3,H)    = 1536

  float* out = (float*)d_out;                          // (T,B,H)
  float* hlast = out + (size_t)T_DIM * B_DIM * H_DIM;  // (1,B,H)

  // workspace: xb(bf16) 16 MB | Wb(bf16 1536x512) 1.5 MB | gx(fp16) 50 MB
  char* ws = (char*)d_ws;
  unsigned short* xb = (unsigned short*)ws;
  unsigned short* Wb = (unsigned short*)(ws + 16777216);
  _Float16* gx = (_Float16*)(ws + 16777216 + 1572864);

  convert_both_kernel<<<4480, 256, 0, stream>>>(x, xb, W_ih, Wb);

  gemm_bf16_kernel<<<768, 512, 0, stream>>>(xb, Wb, gx);

  indgru_scan_kernel<<<256, 64, 0, stream>>>(gx, h0, w_hh, out, hlast);
}